// Round 3
// baseline (314.100 us; speedup 1.0000x reference)
//
#include <hip/hip_runtime.h>
#include <hip/hip_bf16.h>

// GlobalFilter: y = irfft2(rfft2(x, ortho) * W, ortho)  ==  per-channel 14x14
// circular convolution with kernel R_c = (1/196) * Re(IFFT2(Wext_c)).
//
// x: (256, 196, 512) fp32, W: (14, 8, 512, 2) fp32, out: (256, 196, 512) fp32.
// ws: R (196*512 floats = 401,408 B), recomputed every launch.

#define Ns 196          // 14*14 spatial
#define Cc 512
#define CT 32           // channel tile per conv block
#define RS_STRIDE 34    // 32 + 2 pad (decorrelate m-lane banks on b64 reads)
#define CONV_THREADS 448  // 2 batches x 14 rows x 16 channel-pairs

typedef float v2f __attribute__((ext_vector_type(2)));

// ---------------------------------------------------------------------------
// Fused prep (stages A+B in one kernel, T staged in LDS per 16-channel block):
//   T[h,dn,c]  = sum_{w=0..7} W[h,w,c] z^{w*dn} + sum_{w=1..6} conj(W[h2,w,c]) z^{-w*dn}
//   R[dm,dn,c] = (1/196) * Re( sum_h T[h,dn,c] * z^{h*dm} ),  z = e^{i*2pi/14}
// ---------------------------------------------------------------------------
__global__ __launch_bounds__(256) void prep_kernel(const float* __restrict__ cw,
                                                   float* __restrict__ R) {
    __shared__ float Tr[Ns * 16], Ti[Ns * 16];
    __shared__ float cs[14], sn[14];
    const int t = threadIdx.x;
    if (t < 14) {
        float ang = (float)t * 0.44879895051282760549f;  // 2*pi/14
        cs[t] = cosf(ang);
        sn[t] = sinf(ang);
    }
    __syncthreads();

    const int c0 = blockIdx.x * 16;   // 32 blocks x 16 channels

    // stage A -> LDS
    for (int i = t; i < Ns * 16; i += 256) {
        int cc = i & 15, s = i >> 4;
        int h = s / 14, dn = s - h * 14;
        int h2 = (h == 0) ? 0 : (14 - h);
        float tr = 0.0f, ti = 0.0f;
        int k = 0;
        #pragma unroll
        for (int w = 0; w < 8; ++w) {
            const float* p = cw + (size_t)(((h * 8 + w) * 512 + c0 + cc) * 2);
            float Wr = p[0], Wi = p[1];
            tr += Wr * cs[k] - Wi * sn[k];
            ti += Wr * sn[k] + Wi * cs[k];
            k += dn; if (k >= 14) k -= 14;
        }
        int k2 = dn;
        #pragma unroll
        for (int w = 1; w < 7; ++w) {
            const float* p = cw + (size_t)(((h2 * 8 + w) * 512 + c0 + cc) * 2);
            float Wr = p[0], Wi = p[1];
            tr += Wr * cs[k2] - Wi * sn[k2];
            ti -= Wr * sn[k2] + Wi * cs[k2];
            k2 += dn; if (k2 >= 14) k2 -= 14;
        }
        Tr[i] = tr; Ti[i] = ti;
    }
    __syncthreads();

    // stage B -> global R
    for (int i = t; i < Ns * 16; i += 256) {
        int cc = i & 15, s = i >> 4;
        int dm = s / 14, dn = s - dm * 14;
        float acc = 0.0f;
        int kh = 0;
        #pragma unroll
        for (int h = 0; h < 14; ++h) {
            int j = (h * 14 + dn) * 16 + cc;
            acc += Tr[j] * cs[kh] - Ti[j] * sn[kh];
            kh += dm; if (kh >= 14) kh -= 14;
        }
        R[s * 512 + c0 + cc] = acc * (1.0f / 196.0f);
    }
}

// ---------------------------------------------------------------------------
// Main conv. Block = 2 batches x 32 channels. Thread (bsel, m, cp) computes
// y[b0+bsel, m, 0..13, c0+2cp : c0+2cp+2] as packed float2:
//   - native ds_read_b64 for both Rr rows and x values (same dm row per thread)
//   - v_pk_fma_f32 via __builtin_elementwise_fma
//   - each R row / x element read from LDS exactly once per thread
// ---------------------------------------------------------------------------
__global__ __launch_bounds__(CONV_THREADS, 3) void conv_kernel(
        const float* __restrict__ x,
        const float* __restrict__ R,
        float* __restrict__ out) {
    __shared__ float xs[2 * Ns * CT];        // [bsel][s][c], stride 32: 50,176 B
    __shared__ float rs[Ns * RS_STRIDE];     // [s][c], stride 34:      26,656 B

    const int bx = blockIdx.x;               // 2048 blocks
    const int ct = bx & 15;
    const int bp = bx >> 4;
    const int c0 = ct * CT;
    const int b0 = bp * 2;
    const int t  = threadIdx.x;

    const float* xb = x + (size_t)b0 * Ns * Cc + c0;
    const float* Rb = R + c0;
    for (int i = t; i < Ns * CT; i += CONV_THREADS) {
        int s = i >> 5, cc = i & 31;
        xs[i]           = xb[s * Cc + cc];
        xs[Ns * CT + i] = xb[(size_t)Ns * Cc + s * Cc + cc];
        rs[s * RS_STRIDE + cc] = Rb[s * Cc + cc];
    }
    __syncthreads();

    const int cp   = t & 15;          // channel pair -> channels 2cp, 2cp+1
    const int r    = t >> 4;          // 0..27
    const int m    = (r >= 14) ? (r - 14) : r;
    const int bsel = (r >= 14) ? 1 : 0;

    const float* xsb = xs + bsel * Ns * CT + 2 * cp;
    const float* rsc = rs + 2 * cp;

    v2f acc[14];
    #pragma unroll
    for (int n = 0; n < 14; ++n) acc[n] = (v2f)0.0f;

    #pragma unroll 1
    for (int p = 0; p < 14; ++p) {
        int dm = m - p; if (dm < 0) dm += 14;
        const float* rrow = rsc + dm * (14 * RS_STRIDE);
        v2f Rr[14];
        #pragma unroll
        for (int dn = 0; dn < 14; ++dn)
            Rr[dn] = *(const v2f*)(rrow + dn * RS_STRIDE);   // ds_read_b64, imm offsets

        const float* xrow = xsb + p * (14 * CT);
        #pragma unroll
        for (int q = 0; q < 14; ++q) {
            v2f xv = *(const v2f*)(xrow + q * CT);           // ds_read_b64 (broadcast over m-lanes)
            #pragma unroll
            for (int n = 0; n < 14; ++n) {
                int dn = n - q; if (dn < 0) dn += 14;        // compile-time
                acc[n] = __builtin_elementwise_fma(xv, Rr[dn], acc[n]);  // v_pk_fma_f32
            }
        }
    }

    const int b = b0 + bsel;
    float* ob = out + ((size_t)b * Ns + m * 14) * Cc + c0 + 2 * cp;
    #pragma unroll
    for (int n = 0; n < 14; ++n)
        *(v2f*)(ob + n * Cc) = acc[n];                       // global_store_dwordx2
}

extern "C" void kernel_launch(void* const* d_in, const int* in_sizes, int n_in,
                              void* d_out, int out_size, void* d_ws, size_t ws_size,
                              hipStream_t stream) {
    const float* x  = (const float*)d_in[0];
    const float* cw = (const float*)d_in[1];
    float* outp = (float*)d_out;
    float* R = (float*)d_ws;    // 196*512 floats

    prep_kernel<<<32, 256, 0, stream>>>(cw, R);
    conv_kernel<<<128 * 16, CONV_THREADS, 0, stream>>>(x, R, outp);
}